// Round 11
// baseline (94.279 us; speedup 1.0000x reference)
//
#include <hip/hip_runtime.h>
#include <math.h>

#define T_STEPS 1000
#define BETA_1f 0.0001f
#define BETA_Tf 0.02f

// Fused: haar-dwt -> d_t -> 8->4 matvec -> squared-error -> per-block partial,
// with last-finishing-block final reduction (single heavy dispatch).
// Config: 4 px/thread, 256-thread blocks, 2048 blocks = 8192 waves (R2 optimum).
// ws layout: [0..nblocks) float partials | counter (uint) at ws[nblocks].
__global__ __launch_bounds__(256) void fused_loss_kernel(
    const float* __restrict__ x0,
    const float* __restrict__ noise,
    const float* __restrict__ Wm,     // (4,8) row-major [o][c]
    const float* __restrict__ bias,   // (4,)
    const float* __restrict__ temb,   // (1000,4)
    const int*   __restrict__ t,      // (B,)
    float* __restrict__ ws,           // partials + counter
    float* __restrict__ out)
{
    const int idx = blockIdx.x * blockDim.x + threadIdx.x;
    // per batch: 256 rows x 64 thread-cols = 16384 threads
    const int b   = idx >> 14;
    const int rem = idx & 16383;
    const int h   = rem >> 6;
    const int w4  = rem & 63;
    const int lane = threadIdx.x & 63;

    // ---- issue ALL global loads first (12 float4 in flight per thread) ----
    const float* x0b = x0 + (size_t)b * 2 * 512 * 512;
    const float* x1b = x0b + 512 * 512;
    const int roff0 = (2 * h) * 512 + 8 * w4;
    const int roff1 = roff0 + 512;

    float ct_r0[8], ct_r1[8], cb_r0[8], cb_r1[8];
    *(float4*)&ct_r0[0] = *(const float4*)(x0b + roff0);
    *(float4*)&ct_r0[4] = *(const float4*)(x0b + roff0 + 4);
    *(float4*)&ct_r1[0] = *(const float4*)(x0b + roff1);
    *(float4*)&ct_r1[4] = *(const float4*)(x0b + roff1 + 4);
    *(float4*)&cb_r0[0] = *(const float4*)(x1b + roff0);
    *(float4*)&cb_r0[4] = *(const float4*)(x1b + roff0 + 4);
    *(float4*)&cb_r1[0] = *(const float4*)(x1b + roff1);
    *(float4*)&cb_r1[4] = *(const float4*)(x1b + roff1 + 4);

    const float* nb = noise + (size_t)b * 4 * 65536 + h * 256 + 4 * w4;
    float nz[4][4];
    *(float4*)&nz[0][0] = *(const float4*)(nb + 0 * 65536);
    *(float4*)&nz[1][0] = *(const float4*)(nb + 1 * 65536);
    *(float4*)&nz[2][0] = *(const float4*)(nb + 2 * 65536);
    *(float4*)&nz[3][0] = *(const float4*)(nb + 3 * 65536);

    // ---- per-batch diffusion scales, wave-parallel (overlaps with loads) ----
    const int tv = t[b];               // uniform within block
    const float step = (BETA_Tf - BETA_1f) / (float)(T_STEPS - 1);
    float prod = 1.0f;
    {
        const int j0 = lane * 16;      // 64 lanes x 16 = 1024 >= T
#pragma unroll
        for (int k = 0; k < 16; ++k) {
            const int j = j0 + k;
            const float f = (j <= tv && j < T_STEPS) ? (1.0f - (BETA_1f + step * (float)j)) : 1.0f;
            prod *= f;
        }
#pragma unroll
        for (int off = 32; off > 0; off >>= 1) prod *= __shfl_xor(prod, off);
    }
    const float sab   = sqrtf(prod);
    const float somab = sqrtf(1.0f - prod);

    float base[4];
#pragma unroll
    for (int o = 0; o < 4; ++o) base[o] = bias[o] + temb[tv * 4 + o];

    // W into registers (uniform address -> scalar loads)
    float w[32];
#pragma unroll
    for (int i = 0; i < 32; ++i) w[i] = Wm[i];

    float local = 0.0f;

#pragma unroll
    for (int p = 0; p < 4; ++p) {
        const float ca_ = ct_r0[2 * p],     cb_ = ct_r0[2 * p + 1];
        const float cc_ = ct_r1[2 * p],     cd_ = ct_r1[2 * p + 1];
        const float ba_ = cb_r0[2 * p],     bb_ = cb_r0[2 * p + 1];
        const float bc_ = cb_r1[2 * p],     bd_ = cb_r1[2 * p + 1];

        const float tA = (ca_ + cb_ + cc_ + cd_) * 0.5f;
        const float tH = (ca_ + cb_ - cc_ - cd_) * 0.5f;
        const float tV = (ca_ - cb_ + cc_ - cd_) * 0.5f;
        const float tD = (ca_ - cb_ - cc_ + cd_) * 0.5f;
        const float gA = (ba_ + bb_ + bc_ + bd_) * 0.5f;
        const float gH = (ba_ + bb_ - bc_ - bd_) * 0.5f;
        const float gV = (ba_ - bb_ + bc_ - bd_) * 0.5f;
        const float gD = (ba_ - bb_ - bc_ + bd_) * 0.5f;

        float mi[8];
        mi[0] = sab * (tA - gA) + somab * nz[0][p];
        mi[1] = sab * (tH - gH) + somab * nz[1][p];
        mi[2] = sab * (tV - gV) + somab * nz[2][p];
        mi[3] = sab * (tD - gD) + somab * nz[3][p];
        mi[4] = gA; mi[5] = gH; mi[6] = gV; mi[7] = gD;

#pragma unroll
        for (int o = 0; o < 4; ++o) {
            float e = base[o];
#pragma unroll
            for (int c = 0; c < 8; ++c) e = fmaf(w[o * 8 + c], mi[c], e);
            const float d = e - nz[o][p];
            local = fmaf(d, d, local);
        }
    }

    // ---- block reduction -> one partial per block ----
#pragma unroll
    for (int off = 32; off > 0; off >>= 1) local += __shfl_down(local, off);
    __shared__ float ssum[4];
    __shared__ int s_last;
    const int wid = threadIdx.x >> 6;
    if (lane == 0) ssum[wid] = local;
    __syncthreads();

    const int nblk = gridDim.x;
    unsigned int* counter = (unsigned int*)(ws + nblk);
    if (threadIdx.x == 0) {
        ws[blockIdx.x] = ssum[0] + ssum[1] + ssum[2] + ssum[3];
        __threadfence();                               // agent-scope release of partial
        unsigned int old = atomicAdd(counter, 1u);     // device-scope
        s_last = (old == (unsigned int)(nblk - 1)) ? 1 : 0;
    }
    __syncthreads();

    if (s_last) {
        // Last block to finish: all partials are globally visible. Read with
        // agent-scope loads (bypass possibly-stale per-XCD L2 from prior replay),
        // reduce in fixed order -> bitwise-deterministic result.
        __threadfence();                               // acquire
        float acc = 0.0f;
        for (int i = threadIdx.x; i < nblk; i += 256)  // each thread: fixed stride order
            acc += __hip_atomic_load(&ws[i], __ATOMIC_RELAXED, __HIP_MEMORY_SCOPE_AGENT);
#pragma unroll
        for (int off = 32; off > 0; off >>= 1) acc += __shfl_down(acc, off);
        if (lane == 0) ssum[wid] = acc;
        __syncthreads();
        if (threadIdx.x == 0) out[0] = ssum[0] + ssum[1] + ssum[2] + ssum[3];
    }
}

extern "C" void kernel_launch(void* const* d_in, const int* in_sizes, int n_in,
                              void* d_out, int out_size, void* d_ws, size_t ws_size,
                              hipStream_t stream) {
    const float* x0    = (const float*)d_in[0];
    const float* noise = (const float*)d_in[1];
    const float* Wm    = (const float*)d_in[2];
    const float* bias  = (const float*)d_in[3];
    const float* temb  = (const float*)d_in[4];
    const int*   t     = (const int*)d_in[5];
    float* out = (float*)d_out;
    float* ws  = (float*)d_ws;

    const int B = in_sizes[0] / (2 * 512 * 512);   // 32

    const int total  = B * 256 * 64;               // one thread per 4 output pixels
    const int blocks = total / 256;                // 2048 blocks x 256 threads

    // zero the completion counter (lives right after the partials)
    hipMemsetAsync((void*)(ws + blocks), 0, sizeof(unsigned int), stream);

    fused_loss_kernel<<<blocks, 256, 0, stream>>>(x0, noise, Wm, bias, temb, t, ws, out);
}

// Round 12
// 27.584 us; speedup vs baseline: 3.4178x; 3.4178x over previous
//
#include <hip/hip_runtime.h>
#include <math.h>

#define T_STEPS 1000
#define BETA_1f 0.0001f
#define BETA_Tf 0.02f

// Fused: haar-dwt -> d_t -> 8->4 matvec -> squared-error, per-block partial sum to ws.
// Layout: x_0 (B,2,512,512), noise (B,4,256,256). Output pixel grid per batch: 256x256.
// Config: 4 px/thread, 256-thread blocks, 2048 blocks = 8192 waves (measured optimum,
// R2/R5/R6/R7 sweep). Two-dispatch partial-sum structure (R1/R11: any same-address
// device-scope atomic path costs ~60ns x nblocks -> far worse than a 2nd dispatch).
__global__ __launch_bounds__(256) void fused_loss_kernel(
    const float* __restrict__ x0,
    const float* __restrict__ noise,
    const float* __restrict__ Wm,     // (4,8) row-major [o][c]
    const float* __restrict__ bias,   // (4,)
    const float* __restrict__ temb,   // (1000,4)
    const int*   __restrict__ t,      // (B,)
    float* __restrict__ partials)     // ws: one float per block
{
    const int idx = blockIdx.x * blockDim.x + threadIdx.x;
    // per batch: 256 rows x 64 thread-cols = 16384 threads
    const int b   = idx >> 14;
    const int rem = idx & 16383;
    const int h   = rem >> 6;
    const int w4  = rem & 63;
    const int lane = threadIdx.x & 63;

    // ---- issue ALL global loads first (12 float4 in flight per thread) ----
    const float* x0b = x0 + (size_t)b * 2 * 512 * 512;
    const float* x1b = x0b + 512 * 512;
    const int roff0 = (2 * h) * 512 + 8 * w4;
    const int roff1 = roff0 + 512;

    float ct_r0[8], ct_r1[8], cb_r0[8], cb_r1[8];
    *(float4*)&ct_r0[0] = *(const float4*)(x0b + roff0);
    *(float4*)&ct_r0[4] = *(const float4*)(x0b + roff0 + 4);
    *(float4*)&ct_r1[0] = *(const float4*)(x0b + roff1);
    *(float4*)&ct_r1[4] = *(const float4*)(x0b + roff1 + 4);
    *(float4*)&cb_r0[0] = *(const float4*)(x1b + roff0);
    *(float4*)&cb_r0[4] = *(const float4*)(x1b + roff0 + 4);
    *(float4*)&cb_r1[0] = *(const float4*)(x1b + roff1);
    *(float4*)&cb_r1[4] = *(const float4*)(x1b + roff1 + 4);

    const float* nb = noise + (size_t)b * 4 * 65536 + h * 256 + 4 * w4;
    float nz[4][4];
    *(float4*)&nz[0][0] = *(const float4*)(nb + 0 * 65536);
    *(float4*)&nz[1][0] = *(const float4*)(nb + 1 * 65536);
    *(float4*)&nz[2][0] = *(const float4*)(nb + 2 * 65536);
    *(float4*)&nz[3][0] = *(const float4*)(nb + 3 * 65536);

    // ---- per-batch diffusion scales, wave-parallel (overlaps with loads) ----
    const int tv = t[b];               // uniform within block
    const float step = (BETA_Tf - BETA_1f) / (float)(T_STEPS - 1);
    float prod = 1.0f;
    {
        const int j0 = lane * 16;      // 64 lanes x 16 = 1024 >= T
#pragma unroll
        for (int k = 0; k < 16; ++k) {
            const int j = j0 + k;
            const float f = (j <= tv && j < T_STEPS) ? (1.0f - (BETA_1f + step * (float)j)) : 1.0f;
            prod *= f;
        }
#pragma unroll
        for (int off = 32; off > 0; off >>= 1) prod *= __shfl_xor(prod, off);
    }
    const float sab   = sqrtf(prod);
    const float somab = sqrtf(1.0f - prod);

    float base[4];
#pragma unroll
    for (int o = 0; o < 4; ++o) base[o] = bias[o] + temb[tv * 4 + o];

    // W into registers (uniform address -> scalar loads)
    float w[32];
#pragma unroll
    for (int i = 0; i < 32; ++i) w[i] = Wm[i];

    float local = 0.0f;

#pragma unroll
    for (int p = 0; p < 4; ++p) {
        const float ca_ = ct_r0[2 * p],     cb_ = ct_r0[2 * p + 1];
        const float cc_ = ct_r1[2 * p],     cd_ = ct_r1[2 * p + 1];
        const float ba_ = cb_r0[2 * p],     bb_ = cb_r0[2 * p + 1];
        const float bc_ = cb_r1[2 * p],     bd_ = cb_r1[2 * p + 1];

        const float tA = (ca_ + cb_ + cc_ + cd_) * 0.5f;
        const float tH = (ca_ + cb_ - cc_ - cd_) * 0.5f;
        const float tV = (ca_ - cb_ + cc_ - cd_) * 0.5f;
        const float tD = (ca_ - cb_ - cc_ + cd_) * 0.5f;
        const float gA = (ba_ + bb_ + bc_ + bd_) * 0.5f;
        const float gH = (ba_ + bb_ - bc_ - bd_) * 0.5f;
        const float gV = (ba_ - bb_ + bc_ - bd_) * 0.5f;
        const float gD = (ba_ - bb_ - bc_ + bd_) * 0.5f;

        float mi[8];
        mi[0] = sab * (tA - gA) + somab * nz[0][p];
        mi[1] = sab * (tH - gH) + somab * nz[1][p];
        mi[2] = sab * (tV - gV) + somab * nz[2][p];
        mi[3] = sab * (tD - gD) + somab * nz[3][p];
        mi[4] = gA; mi[5] = gH; mi[6] = gV; mi[7] = gD;

#pragma unroll
        for (int o = 0; o < 4; ++o) {
            float e = base[o];
#pragma unroll
            for (int c = 0; c < 8; ++c) e = fmaf(w[o * 8 + c], mi[c], e);
            const float d = e - nz[o][p];
            local = fmaf(d, d, local);
        }
    }

    // ---- block reduction -> one partial per block (no atomics) ----
#pragma unroll
    for (int off = 32; off > 0; off >>= 1) local += __shfl_down(local, off);
    __shared__ float ssum[4];
    const int wid = threadIdx.x >> 6;
    if (lane == 0) ssum[wid] = local;
    __syncthreads();
    if (threadIdx.x == 0) {
        partials[blockIdx.x] = ssum[0] + ssum[1] + ssum[2] + ssum[3];
    }
}

// Final reduce: 256 threads, float4 loads (2048 partials = 512 float4 / 256 threads = 2 each).
__global__ __launch_bounds__(256) void final_reduce_kernel(
    const float* __restrict__ partials, float* __restrict__ out, int n)
{
    const int tid  = threadIdx.x;
    const int lane = tid & 63;
    const int wid  = tid >> 6;
    float local = 0.0f;
    const int nvec = n >> 2;                    // float4 count
    for (int i = tid; i < nvec; i += 256) {
        const float4 v = *(const float4*)(partials + 4 * i);
        local += (v.x + v.y) + (v.z + v.w);
    }
#pragma unroll
    for (int off = 32; off > 0; off >>= 1) local += __shfl_down(local, off);
    __shared__ float ssum[4];
    if (lane == 0) ssum[wid] = local;
    __syncthreads();
    if (tid == 0) out[0] = ssum[0] + ssum[1] + ssum[2] + ssum[3];
}

extern "C" void kernel_launch(void* const* d_in, const int* in_sizes, int n_in,
                              void* d_out, int out_size, void* d_ws, size_t ws_size,
                              hipStream_t stream) {
    const float* x0    = (const float*)d_in[0];
    const float* noise = (const float*)d_in[1];
    const float* Wm    = (const float*)d_in[2];
    const float* bias  = (const float*)d_in[3];
    const float* temb  = (const float*)d_in[4];
    const int*   t     = (const int*)d_in[5];
    float* out = (float*)d_out;
    float* ws  = (float*)d_ws;

    const int B = in_sizes[0] / (2 * 512 * 512);   // 32

    const int total  = B * 256 * 64;               // one thread per 4 output pixels
    const int blocks = total / 256;                // 2048 blocks x 256 threads

    fused_loss_kernel<<<blocks, 256, 0, stream>>>(x0, noise, Wm, bias, temb, t, ws);
    final_reduce_kernel<<<1, 256, 0, stream>>>(ws, out, blocks);
}